// Round 11
// baseline (104.759 us; speedup 1.0000x reference)
//
#include <hip/hip_runtime.h>

typedef unsigned short u16;
typedef unsigned int   u32;
typedef __bf16 bf16x8 __attribute__((ext_vector_type(8)));
typedef float  f32x4  __attribute__((ext_vector_type(4)));

#define KSCALE 0.12751743f  // log2(e)/sqrt(1024/8)

__device__ __forceinline__ u32 cvtpk(float lo, float hi) {
    u32 r;
    asm("v_cvt_pk_bf16_f32 %0, %1, %2" : "=v"(r) : "v"(lo), "v"(hi));
    return r;
}
__device__ __forceinline__ float bf2f(u32 lo16) {
    return __builtin_bit_cast(float, lo16 << 16);
}

// ---------------------------------------------------------------------------
// Phase 1: QKV projection via MFMA (validated R3/R7). grid = 1024 blocks, 256 thr.
// K written PRE-SCALED (log2e/sqrt128), PRE-PERMUTED (attn slot order) and
// PRE-CHUNK-SWIZZLED so attn's K staging is a pure linear copy.
// ---------------------------------------------------------------------------
__global__ __launch_bounds__(256, 4) void qkv_proj(
    const float* __restrict__ x,
    const float* __restrict__ wq, const float* __restrict__ bq,
    const float* __restrict__ wk, const float* __restrict__ bk,
    const float* __restrict__ wv, const float* __restrict__ bv,
    u16* __restrict__ Qb, u16* __restrict__ Kb, u16* __restrict__ Vb)
{
    __shared__ __align__(16) u16 sW[3][32][40];   // rows padded to 80B
    __shared__ float sB[3][32];
    __shared__ __align__(16) u16 sO[8192];        // bounce [64 w][256B row], chunk16 ^ (w&7)
    const int tid = threadIdx.x;
    const int b  = blockIdx.x >> 8;
    const int h0 = (blockIdx.x & 255) * 4;
    const int wid = tid >> 6, lane = tid & 63;
    const int g = lane >> 4, c = lane & 15;

    {
        const float* Ws[3] = {wq, wk, wv};
#pragma unroll
        for (int m = 0; m < 3; m++) {
            const float sc = (m == 1) ? KSCALE : 1.0f;
            for (int i = tid; i < 512; i += 256) {
                float2 v = ((const float2*)Ws[m])[i];
                int co = i >> 4, cip = i & 15;
                ((u32*)&sW[m][co][0])[cip] = cvtpk(v.x * sc, v.y * sc);
            }
        }
        if (tid < 96) {
            const float* Bs[3] = {bq, bk, bv};
            float v = Bs[tid >> 5][tid & 31];
            if ((tid >> 5) == 1) v *= KSCALE;
            ((float*)sB)[tid] = v;
        }
    }

    // x -> B-fragments (shared by all 3 matrices): lane(c,g) elem j = X[8g+j][pos0+c]
    bf16x8 xf[4];
    {
        const float* xb = x + (size_t)b * 2097152 + (size_t)h0 * 64 + wid * 64;
#pragma unroll
        for (int pt = 0; pt < 4; pt++) {
            float f[8];
#pragma unroll
            for (int j = 0; j < 8; j++)
                f[j] = xb[(size_t)(8 * g + j) * 65536 + pt * 16 + c];
            uint4 u;
            u.x = cvtpk(f[0], f[1]); u.y = cvtpk(f[2], f[3]);
            u.z = cvtpk(f[4], f[5]); u.w = cvtpk(f[6], f[7]);
            xf[pt] = __builtin_bit_cast(bf16x8, u);
        }
    }
    __syncthreads();

    u16* outs[3] = {Qb, Kb, Vb};
    const f32x4 zz = {0.f, 0.f, 0.f, 0.f};

#pragma unroll
    for (int m = 0; m < 3; m++) {
        bf16x8 wf[2];
        float4 bias[2];
#pragma unroll
        for (int a = 0; a < 2; a++) {
            wf[a] = __builtin_bit_cast(bf16x8,
                *(const uint4*)((const char*)&sW[m][a * 16 + c][0] + g * 16));
            bias[a] = *(const float4*)&sB[m][a * 16 + g * 4];
        }

        f32x4 o[2][4];
#pragma unroll
        for (int a = 0; a < 2; a++)
#pragma unroll
            for (int pt = 0; pt < 4; pt++)
                o[a][pt] = __builtin_amdgcn_mfma_f32_16x16x32_bf16(wf[a], xf[pt], zz, 0, 0, 0);

        if (m) __syncthreads();   // previous matrix readback complete

#pragma unroll
        for (int a = 0; a < 2; a++)
#pragma unroll
            for (int pt = 0; pt < 4; pt++) {
                int w = pt * 16 + c;
                float v0 = o[a][pt][0] + bias[a].x;
                float v1 = o[a][pt][1] + bias[a].y;
                float v2 = o[a][pt][2] + bias[a].z;
                float v3 = o[a][pt][3] + bias[a].w;
                uint2 st;
                st.x = cvtpk(v0, v1);
                st.y = cvtpk(v2, v3);
                int chunk = (wid * 4 + a * 2 + (g >> 1)) ^ (w & 7);
                *(uint2*)((char*)sO + w * 256 + chunk * 16 + (g & 1) * 8) = st;
            }
        __syncthreads();

        u16* gout = outs[m];
#pragma unroll
        for (int i = 0; i < 4; i++) {
            int L = tid + i * 256;
            int w_ = L >> 4, lc = L & 15;
            uint4 val = *(const uint4*)((const char*)sO + w_ * 256 + ((lc ^ (w_ & 7)) << 4));
            int hh = lc >> 2, sub = lc & 3;
            size_t off;
            if (m == 1) {
                int kv = h0 + hh;
                int q5 = kv & 31;
                int slot = (kv & ~31) | ((q5 & 4) << 2) | ((q5 & 24) >> 1) | (q5 & 3);
                off = (size_t)(b * 64 + w_) * 32768 + slot * 32 + (sub ^ ((slot >> 1) & 3)) * 8;
            } else {
                off = (size_t)(b * 64 + w_) * 32768 + (h0 + hh) * 32 + sub * 8;
            }
            *(uint4*)(gout + off) = val;
        }
    }
}

// ---------------------------------------------------------------------------
// Phase 2: attention — validated monolithic structure (R7-R10), 1024 thr / 16
// waves, 1 block per (b,w) pair. R10 post-mortem: MFMA 33% + VALU 50%, neither
// saturated — pinned phases put all 4 waves/SIMD in the same phase (lockstep).
// This round: 1-deep rotation. Loop body = region 1 {exp/pack(j) || QK(j+1)}
// (independent -> same-wave MFMA/VALU co-issue), pin, region 2 {PV+rowsum(j)}
// in setprio(1). Memory layout, LDS addresses, and math identical to R10.
// Ow now bf16 (halves attn write + finalize read).
// ---------------------------------------------------------------------------
__global__ __launch_bounds__(1024, 2) void attn(
    const u16* __restrict__ Qb, const u16* __restrict__ Kb,
    const u16* __restrict__ Vb, u16* __restrict__ Ow)
{
    __shared__ __align__(16) char sK[65536];
    __shared__ __align__(16) char sV[65536];
    const int tid = threadIdx.x;
    const int p = blockIdx.x;

    {
        const uint4* gK = (const uint4*)(Kb + (size_t)p * 32768);
        uint4* sK4 = (uint4*)sK;
        for (int m = tid; m < 4096; m += 1024)
            sK4[m] = gK[m];                 // linear: image prepared by qkv_proj
        const uint4* gV = (const uint4*)(Vb + (size_t)p * 32768);
        for (int m = tid; m < 4096; m += 1024) {
            uint4 val = gV[m];
            int kv = m >> 2, c0 = (m & 3) * 8;
            const u16* pv = (const u16*)&val;
#pragma unroll
            for (int k = 0; k < 8; k++) {
                int d = c0 + k;
                int chv = (kv >> 3) ^ (d & 7) ^ ((d >> 3) & 3);
                *(u16*)(sV + d * 2048 + (chv << 4) + (kv & 7) * 2) = pv[k];
            }
        }
    }
    __syncthreads();

    const int wid = tid >> 6, lane = tid & 63;
    const int g = lane >> 4, c = lane & 15;

    bf16x8 qf[4];
    {
        const u16* qbase = Qb + (size_t)p * 32768;
#pragma unroll
        for (int nq = 0; nq < 4; nq++) {
            int row = wid * 64 + nq * 16 + c;
            qf[nq] = __builtin_bit_cast(bf16x8, *(const uint4*)(qbase + row * 32 + g * 8));
        }
    }

    // ones A-fragment (bf16 1.0) for the row-sum MFMA
    bf16x8 ones;
    {
        uint4 u; u.x = u.y = u.z = u.w = 0x3F803F80u;
        ones = __builtin_bit_cast(bf16x8, u);
    }

    f32x4 o[4][2];
    f32x4 ls[4];
    const f32x4 zz = {0.f, 0.f, 0.f, 0.f};
#pragma unroll
    for (int nq = 0; nq < 4; nq++) { o[nq][0] = zz; o[nq][1] = zz; ls[nq] = zz; }

    // K/V fragment loads for kv-chunk j (addresses identical to R10)
#define LOADKV(j_, K0, K1, V0, V1)                                              \
    {                                                                           \
        const int kv0_ = (j_) * 32;                                             \
        const int ra_ = kv0_ + c;                                               \
        const int rb_ = ra_ + 16;                                               \
        K0 = __builtin_bit_cast(bf16x8,                                         \
            *(const uint4*)(sK + ra_ * 64 + ((g ^ ((ra_ >> 1) & 3)) << 4)));    \
        K1 = __builtin_bit_cast(bf16x8,                                         \
            *(const uint4*)(sK + rb_ * 64 + ((g ^ ((rb_ >> 1) & 3)) << 4)));    \
        const int cb_ = (kv0_ >> 3) + g;                                        \
        V0 = __builtin_bit_cast(bf16x8,                                         \
            *(const uint4*)(sV + c * 2048 + ((cb_ ^ (c & 7) ^ ((c >> 3) & 3)) << 4)));              \
        V1 = __builtin_bit_cast(bf16x8,                                         \
            *(const uint4*)(sV + (c + 16) * 2048 + ((cb_ ^ (c & 7) ^ (((c + 16) >> 3) & 3)) << 4)));\
    }

    f32x4 sA[4], sB_[4];
    bf16x8 v0c, v1c;
    {
        bf16x8 k0, k1;
        LOADKV(0, k0, k1, v0c, v1c);
#pragma unroll
        for (int nq = 0; nq < 4; nq++) {
            sA[nq]  = __builtin_amdgcn_mfma_f32_16x16x32_bf16(k0, qf[nq], zz, 0, 0, 0);
            sB_[nq] = __builtin_amdgcn_mfma_f32_16x16x32_bf16(k1, qf[nq], zz, 0, 0, 0);
        }
    }

    for (int j = 0; j < 32; j++) {
        bf16x8 k0n, k1n, v0n, v1n;
        f32x4 sAn[4] = {zz, zz, zz, zz};
        f32x4 sBn[4] = {zz, zz, zz, zz};
        const bool more = (j < 31);
        if (more) LOADKV(j + 1, k0n, k1n, v0n, v1n);

        // ---- region 1: exp/pack(j) || QK MFMAs(j+1) — independent streams ----
        bf16x8 pf[4];
#pragma unroll
        for (int nq = 0; nq < 4; nq++) {
            if (more) {
                sAn[nq] = __builtin_amdgcn_mfma_f32_16x16x32_bf16(k0n, qf[nq], zz, 0, 0, 0);
                sBn[nq] = __builtin_amdgcn_mfma_f32_16x16x32_bf16(k1n, qf[nq], zz, 0, 0, 0);
            }
            float p0[4], p1[4];
#pragma unroll
            for (int r = 0; r < 4; r++) {
                p0[r] = __builtin_amdgcn_exp2f(sA[nq][r]);   // scale folded into K
                p1[r] = __builtin_amdgcn_exp2f(sB_[nq][r]);
            }
            uint4 pw;
            pw.x = cvtpk(p0[0], p0[1]);   // kv 8g+0,1
            pw.y = cvtpk(p0[2], p0[3]);   // kv 8g+2,3
            pw.z = cvtpk(p1[0], p1[1]);   // kv 8g+4,5
            pw.w = cvtpk(p1[2], p1[3]);   // kv 8g+6,7
            pf[nq] = __builtin_bit_cast(bf16x8, pw);
        }
        __builtin_amdgcn_sched_barrier(0);

        // ---- region 2: PV + row-sum MFMAs (12), prioritized ----
        __builtin_amdgcn_s_setprio(1);
#pragma unroll
        for (int nq = 0; nq < 4; nq++) {
            o[nq][0] = __builtin_amdgcn_mfma_f32_16x16x32_bf16(v0c, pf[nq], o[nq][0], 0, 0, 0);
            o[nq][1] = __builtin_amdgcn_mfma_f32_16x16x32_bf16(v1c, pf[nq], o[nq][1], 0, 0, 0);
            ls[nq]   = __builtin_amdgcn_mfma_f32_16x16x32_bf16(ones, pf[nq], ls[nq], 0, 0, 0);
        }
        __builtin_amdgcn_s_setprio(0);

        // rotate (register renames)
#pragma unroll
        for (int nq = 0; nq < 4; nq++) { sA[nq] = sAn[nq]; sB_[nq] = sBn[nq]; }
        v0c = v0n; v1c = v1n;
    }
#undef LOADKV

#pragma unroll
    for (int nq = 0; nq < 4; nq++) {
        const float inv = 1.0f / ls[nq][0];   // every lane holds the full row-sum
        const int hq = wid * 64 + nq * 16 + c;
        u16* dst = Ow + (size_t)p * 32768 + hq;
#pragma unroll
        for (int t = 0; t < 2; t++)
#pragma unroll
            for (int r = 0; r < 4; r++) {
                int d = t * 16 + g * 4 + r;
                float v = o[nq][t][r] * inv;
                dst[(size_t)d * 1024] = (u16)cvtpk(v, v);   // lo16 = bf16(v)
            }
    }
}

// ---------------------------------------------------------------------------
// Phase 3: transpose Ow bf16 [pair][d][h] -> out f32 [b][d][h][w], fused
// *sum(w_lin)+b_lin. grid = 2048 blocks (b, d, h-tile of 64), 256 threads.
// ---------------------------------------------------------------------------
__global__ __launch_bounds__(256) void finalize_tr(
    const u16* __restrict__ Ow, const float* __restrict__ w_lin,
    const float* __restrict__ b_lin, float* __restrict__ out)
{
    __shared__ float tile[64][65];
    const int tid = threadIdx.x;
    const int bi = blockIdx.x;
    const int b = bi >> 9, d = (bi >> 4) & 31, ht = bi & 15;
    const int h0 = ht * 64;

    float slin = 0.f;
#pragma unroll
    for (int i = 0; i < 8; i++) slin += w_lin[i];
    const float bl = b_lin[0];

    const int w = tid >> 2, part = tid & 3;
    const u16* src = Ow + (((size_t)b * 64 + w) * 32 + d) * 1024 + h0 + part * 16;
#pragma unroll
    for (int i = 0; i < 2; i++) {
        uint4 v = ((const uint4*)src)[i];            // 8 bf16
        int hh = part * 16 + i * 8;
        u32 a[4] = {v.x, v.y, v.z, v.w};
#pragma unroll
        for (int e = 0; e < 4; e++) {
            tile[w][hh + 2 * e]     = bf2f(a[e] & 0xFFFFu);
            tile[w][hh + 2 * e + 1] = bf2f(a[e] >> 16);
        }
    }
    __syncthreads();

    const int ww = tid & 63, hb = tid >> 6;
    const size_t obase = ((size_t)b * 32 + d) * 1024 + h0;
#pragma unroll
    for (int k = 0; k < 16; k++) {
        int hh = k * 4 + hb;
        out[(obase + hh) * 64 + ww] = tile[ww][hh] * slin + bl;
    }
}

// ---------------------------------------------------------------------------
extern "C" void kernel_launch(void* const* d_in, const int* in_sizes, int n_in,
                              void* d_out, int out_size, void* d_ws, size_t ws_size,
                              hipStream_t stream)
{
    const float* x  = (const float*)d_in[0];
    const float* wq = (const float*)d_in[1];
    const float* bq = (const float*)d_in[2];
    const float* wk = (const float*)d_in[3];
    const float* bk = (const float*)d_in[4];
    const float* wv = (const float*)d_in[5];
    const float* bv = (const float*)d_in[6];
    const float* wl = (const float*)d_in[7];
    const float* bl = (const float*)d_in[8];
    float* out = (float*)d_out;

    char* ws = (char*)d_ws;
    u16*   Qb = (u16*)(ws);                    // 16 MiB bf16 [256][1024][32]
    u16*   Kb = (u16*)(ws + (16u << 20));      // 16 MiB bf16, pre-scaled/permuted/swizzled
    u16*   Vb = (u16*)(ws + (32u << 20));      // 16 MiB bf16 [256][1024][32] pos-major
    u16*   Ow = (u16*)(ws + (48u << 20));      // 16 MiB bf16 [256][32][1024]

    qkv_proj<<<1024, 256, 0, stream>>>(x, wq, bq, wk, bk, wv, bv, Qb, Kb, Vb);
    attn<<<256, 1024, 0, stream>>>(Qb, Kb, Vb, Ow);
    finalize_tr<<<2048, 256, 0, stream>>>(Ow, wl, bl, out);
}

// Round 12
// 92.951 us; speedup vs baseline: 1.1270x; 1.1270x over previous
//
#include <hip/hip_runtime.h>

typedef unsigned short u16;
typedef unsigned int   u32;
typedef __bf16 bf16x8 __attribute__((ext_vector_type(8)));
typedef float  f32x4  __attribute__((ext_vector_type(4)));

#define KSCALE 0.12751743f  // log2(e)/sqrt(1024/8)

__device__ __forceinline__ u32 cvtpk(float lo, float hi) {
    u32 r;
    asm("v_cvt_pk_bf16_f32 %0, %1, %2" : "=v"(r) : "v"(lo), "v"(hi));
    return r;
}
__device__ __forceinline__ float bf2f(u32 lo16) {
    return __builtin_bit_cast(float, lo16 << 16);
}

// ---------------------------------------------------------------------------
// Phase 1: QKV projection via MFMA (validated R3/R7). grid = 1024 blocks, 256 thr.
// K written PRE-SCALED (log2e/sqrt128), PRE-PERMUTED (attn slot order) and
// PRE-CHUNK-SWIZZLED. V now written TRANSPOSED: VT bf16 [pair][d][1024]
// (R1-validated sVT bounce) so attn reads V fragments straight from L2.
// ---------------------------------------------------------------------------
__global__ __launch_bounds__(256, 4) void qkv_proj(
    const float* __restrict__ x,
    const float* __restrict__ wq, const float* __restrict__ bq,
    const float* __restrict__ wk, const float* __restrict__ bk,
    const float* __restrict__ wv, const float* __restrict__ bv,
    u16* __restrict__ Qb, u16* __restrict__ Kb, u16* __restrict__ VT)
{
    __shared__ __align__(16) u16 sW[3][32][40];   // rows padded to 80B
    __shared__ float sB[3][32];
    __shared__ __align__(16) u16 sO[8192];        // bounce [64 w][256B row], chunk16 ^ (w&7)
    __shared__ __align__(16) u16 sVT[32][64][4];  // V bounce: [d][w][hh]
    const int tid = threadIdx.x;
    const int b  = blockIdx.x >> 8;
    const int h0 = (blockIdx.x & 255) * 4;
    const int wid = tid >> 6, lane = tid & 63;
    const int g = lane >> 4, c = lane & 15;

    {
        const float* Ws[3] = {wq, wk, wv};
#pragma unroll
        for (int m = 0; m < 3; m++) {
            const float sc = (m == 1) ? KSCALE : 1.0f;
            for (int i = tid; i < 512; i += 256) {
                float2 v = ((const float2*)Ws[m])[i];
                int co = i >> 4, cip = i & 15;
                ((u32*)&sW[m][co][0])[cip] = cvtpk(v.x * sc, v.y * sc);
            }
        }
        if (tid < 96) {
            const float* Bs[3] = {bq, bk, bv};
            float v = Bs[tid >> 5][tid & 31];
            if ((tid >> 5) == 1) v *= KSCALE;
            ((float*)sB)[tid] = v;
        }
    }

    // x -> B-fragments (shared by all 3 matrices): lane(c,g) elem j = X[8g+j][pos0+c]
    bf16x8 xf[4];
    {
        const float* xb = x + (size_t)b * 2097152 + (size_t)h0 * 64 + wid * 64;
#pragma unroll
        for (int pt = 0; pt < 4; pt++) {
            float f[8];
#pragma unroll
            for (int j = 0; j < 8; j++)
                f[j] = xb[(size_t)(8 * g + j) * 65536 + pt * 16 + c];
            uint4 u;
            u.x = cvtpk(f[0], f[1]); u.y = cvtpk(f[2], f[3]);
            u.z = cvtpk(f[4], f[5]); u.w = cvtpk(f[6], f[7]);
            xf[pt] = __builtin_bit_cast(bf16x8, u);
        }
    }
    __syncthreads();

    u16* outs[2] = {Qb, Kb};
    const f32x4 zz = {0.f, 0.f, 0.f, 0.f};

#pragma unroll
    for (int m = 0; m < 3; m++) {
        bf16x8 wf[2];
        float4 bias[2];
#pragma unroll
        for (int a = 0; a < 2; a++) {
            wf[a] = __builtin_bit_cast(bf16x8,
                *(const uint4*)((const char*)&sW[m][a * 16 + c][0] + g * 16));
            bias[a] = *(const float4*)&sB[m][a * 16 + g * 4];
        }

        f32x4 o[2][4];
#pragma unroll
        for (int a = 0; a < 2; a++)
#pragma unroll
            for (int pt = 0; pt < 4; pt++)
                o[a][pt] = __builtin_amdgcn_mfma_f32_16x16x32_bf16(wf[a], xf[pt], zz, 0, 0, 0);

        if (m) __syncthreads();   // previous matrix readback complete

        if (m < 2) {
#pragma unroll
            for (int a = 0; a < 2; a++)
#pragma unroll
                for (int pt = 0; pt < 4; pt++) {
                    int w = pt * 16 + c;
                    float v0 = o[a][pt][0] + bias[a].x;
                    float v1 = o[a][pt][1] + bias[a].y;
                    float v2 = o[a][pt][2] + bias[a].z;
                    float v3 = o[a][pt][3] + bias[a].w;
                    uint2 st;
                    st.x = cvtpk(v0, v1);
                    st.y = cvtpk(v2, v3);
                    int chunk = (wid * 4 + a * 2 + (g >> 1)) ^ (w & 7);
                    *(uint2*)((char*)sO + w * 256 + chunk * 16 + (g & 1) * 8) = st;
                }
            __syncthreads();

            u16* gout = outs[m];
#pragma unroll
            for (int i = 0; i < 4; i++) {
                int L = tid + i * 256;
                int w_ = L >> 4, lc = L & 15;
                uint4 val = *(const uint4*)((const char*)sO + w_ * 256 + ((lc ^ (w_ & 7)) << 4));
                int hh = lc >> 2, sub = lc & 3;
                size_t off;
                if (m == 1) {
                    int kv = h0 + hh;
                    int q5 = kv & 31;
                    int slot = (kv & ~31) | ((q5 & 4) << 2) | ((q5 & 24) >> 1) | (q5 & 3);
                    off = (size_t)(b * 64 + w_) * 32768 + slot * 32 + (sub ^ ((slot >> 1) & 3)) * 8;
                } else {
                    off = (size_t)(b * 64 + w_) * 32768 + (h0 + hh) * 32 + sub * 8;
                }
                *(uint4*)(gout + off) = val;
            }
            if (m == 1) __syncthreads();   // sO free before V scatter uses sVT? (ordering only)
        } else {
            // V: scatter C-frags transposed into sVT[d][w][hh] (h = h0+wid)
#pragma unroll
            for (int a = 0; a < 2; a++) {
                float bb[4] = {bias[a].x, bias[a].y, bias[a].z, bias[a].w};
#pragma unroll
                for (int pt = 0; pt < 4; pt++)
#pragma unroll
                    for (int r = 0; r < 4; r++) {
                        float v = o[a][pt][r] + bb[r];
                        sVT[a * 16 + g * 4 + r][pt * 16 + c][wid] = (u16)cvtpk(v, v);
                    }
            }
            __syncthreads();
            // readback: [d][w][0..3] -> VT[(b*64+w)][d][h0..h0+3] (8B writes)
#pragma unroll
            for (int i = 0; i < 8; i++) {
                int m_ = tid + i * 256;
                int cc = m_ >> 6, ww = m_ & 63;
                uint2 val = *(const uint2*)&sVT[cc][ww][0];
                *(uint2*)(VT + (size_t)(b * 64 + ww) * 32768 + cc * 1024 + h0) = val;
            }
        }
    }
}

// ---------------------------------------------------------------------------
// Phase 2: attention. 512 blocks = (pair, q-half), 512 thr / 8 waves, each
// wave owns 64 q-rows. K-only LDS (64KB, pre-permuted image) -> 2 blocks/CU
// (4 waves/SIMD) with two INDEPENDENT blocks interleaving their MFMA/VALU
// phases (R10 post-mortem: pinned phases lockstep all waves of one block).
// V fragments read directly from VT global (L2-resident, 64KB/pair; m169:
// don't stage what L2 fits). amdgpu_waves_per_eu(4,4) pins the VGPR budget
// at 128 (R8-R11: allocator otherwise shrinks to 64 chasing 8 waves/EU).
// Phases per j: {QK MFMA} |pin| {V-loads + exp/pack} |pin| {PV+rowsum, prio}.
// ---------------------------------------------------------------------------
extern "C" __global__ __attribute__((amdgpu_flat_work_group_size(512, 512), amdgpu_waves_per_eu(4, 4)))
void attn(const u16* __restrict__ Qb, const u16* __restrict__ Kb,
          const u16* __restrict__ VT, u16* __restrict__ Ow)
{
    __shared__ __align__(16) char sK[65536];
    const int tid = threadIdx.x;
    const int p  = blockIdx.x >> 1;
    const int qh = blockIdx.x & 1;

    {
        const uint4* gK = (const uint4*)(Kb + (size_t)p * 32768);
        uint4* sK4 = (uint4*)sK;
        for (int m = tid; m < 4096; m += 512)
            sK4[m] = gK[m];                 // linear: image prepared by qkv_proj
    }
    __syncthreads();

    const int wid = tid >> 6, lane = tid & 63;
    const int g = lane >> 4, c = lane & 15;

    bf16x8 qf[4];
    {
        const u16* qbase = Qb + (size_t)p * 32768 + (size_t)qh * 512 * 32;
#pragma unroll
        for (int nq = 0; nq < 4; nq++) {
            int row = wid * 64 + nq * 16 + c;
            qf[nq] = __builtin_bit_cast(bf16x8, *(const uint4*)(qbase + row * 32 + g * 8));
        }
    }

    // ones A-fragment (bf16 1.0) for the row-sum MFMA
    bf16x8 ones;
    {
        uint4 u; u.x = u.y = u.z = u.w = 0x3F803F80u;
        ones = __builtin_bit_cast(bf16x8, u);
    }

    const u16* vt0 = VT + (size_t)p * 32768 + (size_t)c * 1024;        // d = c
    const u16* vt1 = VT + (size_t)p * 32768 + (size_t)(c + 16) * 1024; // d = c+16

    f32x4 o[4][2];
    f32x4 ls[4];
    const f32x4 zz = {0.f, 0.f, 0.f, 0.f};
#pragma unroll
    for (int nq = 0; nq < 4; nq++) { o[nq][0] = zz; o[nq][1] = zz; ls[nq] = zz; }

    for (int j = 0; j < 32; j++) {
        const int kv0 = j * 32;
        const int ra = kv0 + c;          // tile X slot row
        const int rb = ra + 16;          // tile Y slot row
        bf16x8 k0 = __builtin_bit_cast(bf16x8,
            *(const uint4*)(sK + ra * 64 + ((g ^ ((ra >> 1) & 3)) << 4)));
        bf16x8 k1 = __builtin_bit_cast(bf16x8,
            *(const uint4*)(sK + rb * 64 + ((g ^ ((rb >> 1) & 3)) << 4)));

        // ---- phase 1: all QK^T MFMAs (8) ----
        f32x4 sA[4], sB_[4];
#pragma unroll
        for (int nq = 0; nq < 4; nq++) {
            sA[nq]  = __builtin_amdgcn_mfma_f32_16x16x32_bf16(k0, qf[nq], zz, 0, 0, 0);
            sB_[nq] = __builtin_amdgcn_mfma_f32_16x16x32_bf16(k1, qf[nq], zz, 0, 0, 0);
        }
        __builtin_amdgcn_sched_barrier(0);

        // ---- phase 2: V global loads (L2) + exp/pack — loads hide under exp ----
        bf16x8 v0 = __builtin_bit_cast(bf16x8, *(const uint4*)(vt0 + kv0 + g * 8));
        bf16x8 v1 = __builtin_bit_cast(bf16x8, *(const uint4*)(vt1 + kv0 + g * 8));
        bf16x8 pf[4];
#pragma unroll
        for (int nq = 0; nq < 4; nq++) {
            float p0[4], p1[4];
#pragma unroll
            for (int r = 0; r < 4; r++) {
                p0[r] = __builtin_amdgcn_exp2f(sA[nq][r]);   // scale folded into K
                p1[r] = __builtin_amdgcn_exp2f(sB_[nq][r]);
            }
            uint4 pw;
            pw.x = cvtpk(p0[0], p0[1]);   // kv 8g+0,1
            pw.y = cvtpk(p0[2], p0[3]);   // kv 8g+2,3
            pw.z = cvtpk(p1[0], p1[1]);   // kv 8g+4,5
            pw.w = cvtpk(p1[2], p1[3]);   // kv 8g+6,7
            pf[nq] = __builtin_bit_cast(bf16x8, pw);
        }
        __builtin_amdgcn_sched_barrier(0);

        // ---- phase 3: PV + row-sum MFMAs (12), prioritized ----
        __builtin_amdgcn_s_setprio(1);
#pragma unroll
        for (int nq = 0; nq < 4; nq++) {
            o[nq][0] = __builtin_amdgcn_mfma_f32_16x16x32_bf16(v0, pf[nq], o[nq][0], 0, 0, 0);
            o[nq][1] = __builtin_amdgcn_mfma_f32_16x16x32_bf16(v1, pf[nq], o[nq][1], 0, 0, 0);
            ls[nq]   = __builtin_amdgcn_mfma_f32_16x16x32_bf16(ones, pf[nq], ls[nq], 0, 0, 0);
        }
        __builtin_amdgcn_s_setprio(0);
    }

#pragma unroll
    for (int nq = 0; nq < 4; nq++) {
        const float inv = 1.0f / ls[nq][0];   // every lane holds the full row-sum
        const int hq = qh * 512 + wid * 64 + nq * 16 + c;
        u16* dst = Ow + (size_t)p * 32768 + hq;
#pragma unroll
        for (int t = 0; t < 2; t++)
#pragma unroll
            for (int r = 0; r < 4; r++) {
                int d = t * 16 + g * 4 + r;
                float v = o[nq][t][r] * inv;
                dst[(size_t)d * 1024] = (u16)cvtpk(v, v);   // lo16 = bf16(v)
            }
    }
}

// ---------------------------------------------------------------------------
// Phase 3: transpose Ow bf16 [pair][d][h] -> out f32 [b][d][h][w], fused
// *sum(w_lin)+b_lin. grid = 2048 blocks (b, d, h-tile of 64), 256 threads.
// (Validated R11.)
// ---------------------------------------------------------------------------
__global__ __launch_bounds__(256) void finalize_tr(
    const u16* __restrict__ Ow, const float* __restrict__ w_lin,
    const float* __restrict__ b_lin, float* __restrict__ out)
{
    __shared__ float tile[64][65];
    const int tid = threadIdx.x;
    const int bi = blockIdx.x;
    const int b = bi >> 9, d = (bi >> 4) & 31, ht = bi & 15;
    const int h0 = ht * 64;

    float slin = 0.f;
#pragma unroll
    for (int i = 0; i < 8; i++) slin += w_lin[i];
    const float bl = b_lin[0];

    const int w = tid >> 2, part = tid & 3;
    const u16* src = Ow + (((size_t)b * 64 + w) * 32 + d) * 1024 + h0 + part * 16;
#pragma unroll
    for (int i = 0; i < 2; i++) {
        uint4 v = ((const uint4*)src)[i];            // 8 bf16
        int hh = part * 16 + i * 8;
        u32 a[4] = {v.x, v.y, v.z, v.w};
#pragma unroll
        for (int e = 0; e < 4; e++) {
            tile[w][hh + 2 * e]     = bf2f(a[e] & 0xFFFFu);
            tile[w][hh + 2 * e + 1] = bf2f(a[e] >> 16);
        }
    }
    __syncthreads();

    const int ww = tid & 63, hb = tid >> 6;
    const size_t obase = ((size_t)b * 32 + d) * 1024 + h0;
#pragma unroll
    for (int k = 0; k < 16; k++) {
        int hh = k * 4 + hb;
        out[(obase + hh) * 64 + ww] = tile[ww][hh] * slin + bl;
    }
}

// ---------------------------------------------------------------------------
extern "C" void kernel_launch(void* const* d_in, const int* in_sizes, int n_in,
                              void* d_out, int out_size, void* d_ws, size_t ws_size,
                              hipStream_t stream)
{
    const float* x  = (const float*)d_in[0];
    const float* wq = (const float*)d_in[1];
    const float* bq = (const float*)d_in[2];
    const float* wk = (const float*)d_in[3];
    const float* bk = (const float*)d_in[4];
    const float* wv = (const float*)d_in[5];
    const float* bv = (const float*)d_in[6];
    const float* wl = (const float*)d_in[7];
    const float* bl = (const float*)d_in[8];
    float* out = (float*)d_out;

    char* ws = (char*)d_ws;
    u16*   Qb = (u16*)(ws);                    // 16 MiB bf16 [256][1024][32]
    u16*   Kb = (u16*)(ws + (16u << 20));      // 16 MiB bf16, pre-scaled/permuted/swizzled
    u16*   VT = (u16*)(ws + (32u << 20));      // 16 MiB bf16 [256][32][1024] (V transposed)
    u16*   Ow = (u16*)(ws + (48u << 20));      // 16 MiB bf16 [256][32][1024]

    qkv_proj<<<1024, 256, 0, stream>>>(x, wq, bq, wk, bk, wv, bv, Qb, Kb, VT);
    attn<<<512, 512, 0, stream>>>(Qb, Kb, VT, Ow);
    finalize_tr<<<2048, 256, 0, stream>>>(Ow, wl, bl, out);
}

// Round 13
// 71.443 us; speedup vs baseline: 1.4663x; 1.3010x over previous
//
#include <hip/hip_runtime.h>

typedef unsigned short u16;
typedef unsigned int   u32;
typedef __bf16 bf16x8 __attribute__((ext_vector_type(8)));
typedef float  f32x4  __attribute__((ext_vector_type(4)));

#define KSCALE 0.12751743f  // log2(e)/sqrt(1024/8)

__device__ __forceinline__ u32 cvtpk(float lo, float hi) {
    u32 r;
    asm("v_cvt_pk_bf16_f32 %0, %1, %2" : "=v"(r) : "v"(lo), "v"(hi));
    return r;
}
__device__ __forceinline__ float bf2f(u32 lo16) {
    return __builtin_bit_cast(float, lo16 << 16);
}

// ---------------------------------------------------------------------------
// Phase 1: QKV projection via MFMA (validated R3/R7/R10/R11 — the fast
// Vb-pos-major version; R12's VT variant write-amplified and is reverted).
// grid = 1024 blocks, 256 thr. K written PRE-SCALED, PRE-PERMUTED,
// PRE-CHUNK-SWIZZLED so attn's K staging is a pure linear copy.
// ---------------------------------------------------------------------------
__global__ __launch_bounds__(256, 4) void qkv_proj(
    const float* __restrict__ x,
    const float* __restrict__ wq, const float* __restrict__ bq,
    const float* __restrict__ wk, const float* __restrict__ bk,
    const float* __restrict__ wv, const float* __restrict__ bv,
    u16* __restrict__ Qb, u16* __restrict__ Kb, u16* __restrict__ Vb)
{
    __shared__ __align__(16) u16 sW[3][32][40];   // rows padded to 80B
    __shared__ float sB[3][32];
    __shared__ __align__(16) u16 sO[8192];        // bounce [64 w][256B row], chunk16 ^ (w&7)
    const int tid = threadIdx.x;
    const int b  = blockIdx.x >> 8;
    const int h0 = (blockIdx.x & 255) * 4;
    const int wid = tid >> 6, lane = tid & 63;
    const int g = lane >> 4, c = lane & 15;

    {
        const float* Ws[3] = {wq, wk, wv};
#pragma unroll
        for (int m = 0; m < 3; m++) {
            const float sc = (m == 1) ? KSCALE : 1.0f;
            for (int i = tid; i < 512; i += 256) {
                float2 v = ((const float2*)Ws[m])[i];
                int co = i >> 4, cip = i & 15;
                ((u32*)&sW[m][co][0])[cip] = cvtpk(v.x * sc, v.y * sc);
            }
        }
        if (tid < 96) {
            const float* Bs[3] = {bq, bk, bv};
            float v = Bs[tid >> 5][tid & 31];
            if ((tid >> 5) == 1) v *= KSCALE;
            ((float*)sB)[tid] = v;
        }
    }

    // x -> B-fragments (shared by all 3 matrices): lane(c,g) elem j = X[8g+j][pos0+c]
    bf16x8 xf[4];
    {
        const float* xb = x + (size_t)b * 2097152 + (size_t)h0 * 64 + wid * 64;
#pragma unroll
        for (int pt = 0; pt < 4; pt++) {
            float f[8];
#pragma unroll
            for (int j = 0; j < 8; j++)
                f[j] = xb[(size_t)(8 * g + j) * 65536 + pt * 16 + c];
            uint4 u;
            u.x = cvtpk(f[0], f[1]); u.y = cvtpk(f[2], f[3]);
            u.z = cvtpk(f[4], f[5]); u.w = cvtpk(f[6], f[7]);
            xf[pt] = __builtin_bit_cast(bf16x8, u);
        }
    }
    __syncthreads();

    u16* outs[3] = {Qb, Kb, Vb};
    const f32x4 zz = {0.f, 0.f, 0.f, 0.f};

#pragma unroll
    for (int m = 0; m < 3; m++) {
        bf16x8 wf[2];
        float4 bias[2];
#pragma unroll
        for (int a = 0; a < 2; a++) {
            wf[a] = __builtin_bit_cast(bf16x8,
                *(const uint4*)((const char*)&sW[m][a * 16 + c][0] + g * 16));
            bias[a] = *(const float4*)&sB[m][a * 16 + g * 4];
        }

        f32x4 o[2][4];
#pragma unroll
        for (int a = 0; a < 2; a++)
#pragma unroll
            for (int pt = 0; pt < 4; pt++)
                o[a][pt] = __builtin_amdgcn_mfma_f32_16x16x32_bf16(wf[a], xf[pt], zz, 0, 0, 0);

        if (m) __syncthreads();   // previous matrix readback complete

#pragma unroll
        for (int a = 0; a < 2; a++)
#pragma unroll
            for (int pt = 0; pt < 4; pt++) {
                int w = pt * 16 + c;
                float v0 = o[a][pt][0] + bias[a].x;
                float v1 = o[a][pt][1] + bias[a].y;
                float v2 = o[a][pt][2] + bias[a].z;
                float v3 = o[a][pt][3] + bias[a].w;
                uint2 st;
                st.x = cvtpk(v0, v1);
                st.y = cvtpk(v2, v3);
                int chunk = (wid * 4 + a * 2 + (g >> 1)) ^ (w & 7);
                *(uint2*)((char*)sO + w * 256 + chunk * 16 + (g & 1) * 8) = st;
            }
        __syncthreads();

        u16* gout = outs[m];
#pragma unroll
        for (int i = 0; i < 4; i++) {
            int L = tid + i * 256;
            int w_ = L >> 4, lc = L & 15;
            uint4 val = *(const uint4*)((const char*)sO + w_ * 256 + ((lc ^ (w_ & 7)) << 4));
            int hh = lc >> 2, sub = lc & 3;
            size_t off;
            if (m == 1) {
                int kv = h0 + hh;
                int q5 = kv & 31;
                int slot = (kv & ~31) | ((q5 & 4) << 2) | ((q5 & 24) >> 1) | (q5 & 3);
                off = (size_t)(b * 64 + w_) * 32768 + slot * 32 + (sub ^ ((slot >> 1) & 3)) * 8;
            } else {
                off = (size_t)(b * 64 + w_) * 32768 + (h0 + hh) * 32 + sub * 8;
            }
            *(uint4*)(gout + off) = val;
        }
    }
}

// ---------------------------------------------------------------------------
// Phase 2: attention — R10's VALIDATED kernel (48.8us): 1024 thr / 16 waves,
// 1 block per (b,w) pair, K+V in LDS, three sched_barrier-pinned phases per
// j-chunk {8 QK MFMA} | {32 exp2 + 16 cvtpk} | {12 PV+rowsum MFMA}, ones-MFMA
// row-sum. ONLY delta vs R10: epilogue writes Ow as bf16 (validated R11).
// Register note: o/ls/sA live in AGPRs; arch-VGPR 60 + AGPR ~64 ≈ the full
// 128/wave unified budget at 4 waves/SIMD — no headroom for deeper ILP here.
// ---------------------------------------------------------------------------
__global__ __launch_bounds__(1024, 2) void attn(
    const u16* __restrict__ Qb, const u16* __restrict__ Kb,
    const u16* __restrict__ Vb, u16* __restrict__ Ow)
{
    __shared__ __align__(16) char sK[65536];
    __shared__ __align__(16) char sV[65536];
    const int tid = threadIdx.x;
    const int p = blockIdx.x;

    {
        const uint4* gK = (const uint4*)(Kb + (size_t)p * 32768);
        uint4* sK4 = (uint4*)sK;
        for (int m = tid; m < 4096; m += 1024)
            sK4[m] = gK[m];                 // linear: image prepared by qkv_proj
        const uint4* gV = (const uint4*)(Vb + (size_t)p * 32768);
        for (int m = tid; m < 4096; m += 1024) {
            uint4 val = gV[m];
            int kv = m >> 2, c0 = (m & 3) * 8;
            const u16* pv = (const u16*)&val;
#pragma unroll
            for (int k = 0; k < 8; k++) {
                int d = c0 + k;
                int chv = (kv >> 3) ^ (d & 7) ^ ((d >> 3) & 3);
                *(u16*)(sV + d * 2048 + (chv << 4) + (kv & 7) * 2) = pv[k];
            }
        }
    }
    __syncthreads();

    const int wid = tid >> 6, lane = tid & 63;
    const int g = lane >> 4, c = lane & 15;

    bf16x8 qf[4];
    {
        const u16* qbase = Qb + (size_t)p * 32768;
#pragma unroll
        for (int nq = 0; nq < 4; nq++) {
            int row = wid * 64 + nq * 16 + c;
            qf[nq] = __builtin_bit_cast(bf16x8, *(const uint4*)(qbase + row * 32 + g * 8));
        }
    }

    // ones A-fragment (bf16 1.0) for the row-sum MFMA
    bf16x8 ones;
    {
        uint4 u; u.x = u.y = u.z = u.w = 0x3F803F80u;
        ones = __builtin_bit_cast(bf16x8, u);
    }

    f32x4 o[4][2];
    f32x4 ls[4];
    const f32x4 zz = {0.f, 0.f, 0.f, 0.f};
#pragma unroll
    for (int nq = 0; nq < 4; nq++) { o[nq][0] = zz; o[nq][1] = zz; ls[nq] = zz; }

    for (int j = 0; j < 32; j++) {
        const int kv0 = j * 32;
        const int ra = kv0 + c;          // tile X slot row
        const int rb = ra + 16;          // tile Y slot row
        bf16x8 k0 = __builtin_bit_cast(bf16x8,
            *(const uint4*)(sK + ra * 64 + ((g ^ ((ra >> 1) & 3)) << 4)));
        bf16x8 k1 = __builtin_bit_cast(bf16x8,
            *(const uint4*)(sK + rb * 64 + ((g ^ ((rb >> 1) & 3)) << 4)));
        const int cb = (kv0 >> 3) + g;
        bf16x8 v0 = __builtin_bit_cast(bf16x8,
            *(const uint4*)(sV + c * 2048 + ((cb ^ (c & 7) ^ ((c >> 3) & 3)) << 4)));
        bf16x8 v1 = __builtin_bit_cast(bf16x8,
            *(const uint4*)(sV + (c + 16) * 2048 + ((cb ^ (c & 7) ^ (((c + 16) >> 3) & 3)) << 4)));

        // ---- phase 1: all QK^T MFMAs (8) ----
        f32x4 sA[4], sB_[4];
#pragma unroll
        for (int nq = 0; nq < 4; nq++) {
            sA[nq]  = __builtin_amdgcn_mfma_f32_16x16x32_bf16(k0, qf[nq], zz, 0, 0, 0);
            sB_[nq] = __builtin_amdgcn_mfma_f32_16x16x32_bf16(k1, qf[nq], zz, 0, 0, 0);
        }
        __builtin_amdgcn_sched_barrier(0);

        // ---- phase 2: all exp2 + pack (32 trans + 16 cvtpk) ----
        bf16x8 pf[4];
#pragma unroll
        for (int nq = 0; nq < 4; nq++) {
            float p0[4], p1[4];
#pragma unroll
            for (int r = 0; r < 4; r++) {
                p0[r] = __builtin_amdgcn_exp2f(sA[nq][r]);   // scale folded into K
                p1[r] = __builtin_amdgcn_exp2f(sB_[nq][r]);
            }
            uint4 pw;
            pw.x = cvtpk(p0[0], p0[1]);   // kv 8g+0,1
            pw.y = cvtpk(p0[2], p0[3]);   // kv 8g+2,3
            pw.z = cvtpk(p1[0], p1[1]);   // kv 8g+4,5
            pw.w = cvtpk(p1[2], p1[3]);   // kv 8g+6,7
            pf[nq] = __builtin_bit_cast(bf16x8, pw);
        }
        __builtin_amdgcn_sched_barrier(0);

        // ---- phase 3: all PV + row-sum MFMAs (12), prioritized ----
        __builtin_amdgcn_s_setprio(1);
#pragma unroll
        for (int nq = 0; nq < 4; nq++) {
            o[nq][0] = __builtin_amdgcn_mfma_f32_16x16x32_bf16(v0, pf[nq], o[nq][0], 0, 0, 0);
            o[nq][1] = __builtin_amdgcn_mfma_f32_16x16x32_bf16(v1, pf[nq], o[nq][1], 0, 0, 0);
            ls[nq]   = __builtin_amdgcn_mfma_f32_16x16x32_bf16(ones, pf[nq], ls[nq], 0, 0, 0);
        }
        __builtin_amdgcn_s_setprio(0);
    }

#pragma unroll
    for (int nq = 0; nq < 4; nq++) {
        const float inv = 1.0f / ls[nq][0];   // every lane holds the full row-sum
        const int hq = wid * 64 + nq * 16 + c;
        u16* dst = Ow + (size_t)p * 32768 + hq;
#pragma unroll
        for (int t = 0; t < 2; t++)
#pragma unroll
            for (int r = 0; r < 4; r++) {
                int d = t * 16 + g * 4 + r;
                float v = o[nq][t][r] * inv;
                dst[(size_t)d * 1024] = (u16)cvtpk(v, v);   // lo16 = bf16(v)
            }
    }
}

// ---------------------------------------------------------------------------
// Phase 3: transpose Ow bf16 [pair][d][h] -> out f32 [b][d][h][w], fused
// *sum(w_lin)+b_lin. grid = 2048 blocks (b, d, h-tile of 64), 256 threads.
// (Validated R11/R12.)
// ---------------------------------------------------------------------------
__global__ __launch_bounds__(256) void finalize_tr(
    const u16* __restrict__ Ow, const float* __restrict__ w_lin,
    const float* __restrict__ b_lin, float* __restrict__ out)
{
    __shared__ float tile[64][65];
    const int tid = threadIdx.x;
    const int bi = blockIdx.x;
    const int b = bi >> 9, d = (bi >> 4) & 31, ht = bi & 15;
    const int h0 = ht * 64;

    float slin = 0.f;
#pragma unroll
    for (int i = 0; i < 8; i++) slin += w_lin[i];
    const float bl = b_lin[0];

    const int w = tid >> 2, part = tid & 3;
    const u16* src = Ow + (((size_t)b * 64 + w) * 32 + d) * 1024 + h0 + part * 16;
#pragma unroll
    for (int i = 0; i < 2; i++) {
        uint4 v = ((const uint4*)src)[i];            // 8 bf16
        int hh = part * 16 + i * 8;
        u32 a[4] = {v.x, v.y, v.z, v.w};
#pragma unroll
        for (int e = 0; e < 4; e++) {
            tile[w][hh + 2 * e]     = bf2f(a[e] & 0xFFFFu);
            tile[w][hh + 2 * e + 1] = bf2f(a[e] >> 16);
        }
    }
    __syncthreads();

    const int ww = tid & 63, hb = tid >> 6;
    const size_t obase = ((size_t)b * 32 + d) * 1024 + h0;
#pragma unroll
    for (int k = 0; k < 16; k++) {
        int hh = k * 4 + hb;
        out[(obase + hh) * 64 + ww] = tile[ww][hh] * slin + bl;
    }
}

// ---------------------------------------------------------------------------
extern "C" void kernel_launch(void* const* d_in, const int* in_sizes, int n_in,
                              void* d_out, int out_size, void* d_ws, size_t ws_size,
                              hipStream_t stream)
{
    const float* x  = (const float*)d_in[0];
    const float* wq = (const float*)d_in[1];
    const float* bq = (const float*)d_in[2];
    const float* wk = (const float*)d_in[3];
    const float* bk = (const float*)d_in[4];
    const float* wv = (const float*)d_in[5];
    const float* bv = (const float*)d_in[6];
    const float* wl = (const float*)d_in[7];
    const float* bl = (const float*)d_in[8];
    float* out = (float*)d_out;

    char* ws = (char*)d_ws;
    u16*   Qb = (u16*)(ws);                    // 16 MiB bf16 [256][1024][32]
    u16*   Kb = (u16*)(ws + (16u << 20));      // 16 MiB bf16, pre-scaled/permuted/swizzled
    u16*   Vb = (u16*)(ws + (32u << 20));      // 16 MiB bf16 [256][1024][32] pos-major
    u16*   Ow = (u16*)(ws + (48u << 20));      // 16 MiB bf16 [256][32][1024]

    qkv_proj<<<1024, 256, 0, stream>>>(x, wq, bq, wk, bk, wv, bv, Qb, Kb, Vb);
    attn<<<256, 1024, 0, stream>>>(Qb, Kb, Vb, Ow);
    finalize_tr<<<2048, 256, 0, stream>>>(Ow, wl, bl, out);
}

// Round 14
// 69.574 us; speedup vs baseline: 1.5057x; 1.0269x over previous
//
#include <hip/hip_runtime.h>

typedef unsigned short u16;
typedef unsigned int   u32;
typedef __bf16 bf16x8 __attribute__((ext_vector_type(8)));
typedef float  f32x4  __attribute__((ext_vector_type(4)));

#define KSCALE 0.12751743f  // log2(e)/sqrt(1024/8)

__device__ __forceinline__ u32 cvtpk(float lo, float hi) {
    u32 r;
    asm("v_cvt_pk_bf16_f32 %0, %1, %2" : "=v"(r) : "v"(lo), "v"(hi));
    return r;
}
__device__ __forceinline__ float bf2f(u32 lo16) {
    return __builtin_bit_cast(float, lo16 << 16);
}

// ---------------------------------------------------------------------------
// Phase 1: QKV projection via MFMA (validated R3/R7/R10/R13). grid = 1024
// blocks, 256 thr. K written PRE-SCALED, PRE-PERMUTED, PRE-CHUNK-SWIZZLED so
// attn's K staging is a pure linear copy. Vb pos-major.
// ---------------------------------------------------------------------------
__global__ __launch_bounds__(256, 4) void qkv_proj(
    const float* __restrict__ x,
    const float* __restrict__ wq, const float* __restrict__ bq,
    const float* __restrict__ wk, const float* __restrict__ bk,
    const float* __restrict__ wv, const float* __restrict__ bv,
    u16* __restrict__ Qb, u16* __restrict__ Kb, u16* __restrict__ Vb)
{
    __shared__ __align__(16) u16 sW[3][32][40];   // rows padded to 80B
    __shared__ float sB[3][32];
    __shared__ __align__(16) u16 sO[8192];        // bounce [64 w][256B row], chunk16 ^ (w&7)
    const int tid = threadIdx.x;
    const int b  = blockIdx.x >> 8;
    const int h0 = (blockIdx.x & 255) * 4;
    const int wid = tid >> 6, lane = tid & 63;
    const int g = lane >> 4, c = lane & 15;

    {
        const float* Ws[3] = {wq, wk, wv};
#pragma unroll
        for (int m = 0; m < 3; m++) {
            const float sc = (m == 1) ? KSCALE : 1.0f;
            for (int i = tid; i < 512; i += 256) {
                float2 v = ((const float2*)Ws[m])[i];
                int co = i >> 4, cip = i & 15;
                ((u32*)&sW[m][co][0])[cip] = cvtpk(v.x * sc, v.y * sc);
            }
        }
        if (tid < 96) {
            const float* Bs[3] = {bq, bk, bv};
            float v = Bs[tid >> 5][tid & 31];
            if ((tid >> 5) == 1) v *= KSCALE;
            ((float*)sB)[tid] = v;
        }
    }

    // x -> B-fragments (shared by all 3 matrices): lane(c,g) elem j = X[8g+j][pos0+c]
    bf16x8 xf[4];
    {
        const float* xb = x + (size_t)b * 2097152 + (size_t)h0 * 64 + wid * 64;
#pragma unroll
        for (int pt = 0; pt < 4; pt++) {
            float f[8];
#pragma unroll
            for (int j = 0; j < 8; j++)
                f[j] = xb[(size_t)(8 * g + j) * 65536 + pt * 16 + c];
            uint4 u;
            u.x = cvtpk(f[0], f[1]); u.y = cvtpk(f[2], f[3]);
            u.z = cvtpk(f[4], f[5]); u.w = cvtpk(f[6], f[7]);
            xf[pt] = __builtin_bit_cast(bf16x8, u);
        }
    }
    __syncthreads();

    u16* outs[3] = {Qb, Kb, Vb};
    const f32x4 zz = {0.f, 0.f, 0.f, 0.f};

#pragma unroll
    for (int m = 0; m < 3; m++) {
        bf16x8 wf[2];
        float4 bias[2];
#pragma unroll
        for (int a = 0; a < 2; a++) {
            wf[a] = __builtin_bit_cast(bf16x8,
                *(const uint4*)((const char*)&sW[m][a * 16 + c][0] + g * 16));
            bias[a] = *(const float4*)&sB[m][a * 16 + g * 4];
        }

        f32x4 o[2][4];
#pragma unroll
        for (int a = 0; a < 2; a++)
#pragma unroll
            for (int pt = 0; pt < 4; pt++)
                o[a][pt] = __builtin_amdgcn_mfma_f32_16x16x32_bf16(wf[a], xf[pt], zz, 0, 0, 0);

        if (m) __syncthreads();   // previous matrix readback complete

#pragma unroll
        for (int a = 0; a < 2; a++)
#pragma unroll
            for (int pt = 0; pt < 4; pt++) {
                int w = pt * 16 + c;
                float v0 = o[a][pt][0] + bias[a].x;
                float v1 = o[a][pt][1] + bias[a].y;
                float v2 = o[a][pt][2] + bias[a].z;
                float v3 = o[a][pt][3] + bias[a].w;
                uint2 st;
                st.x = cvtpk(v0, v1);
                st.y = cvtpk(v2, v3);
                int chunk = (wid * 4 + a * 2 + (g >> 1)) ^ (w & 7);
                *(uint2*)((char*)sO + w * 256 + chunk * 16 + (g & 1) * 8) = st;
            }
        __syncthreads();

        u16* gout = outs[m];
#pragma unroll
        for (int i = 0; i < 4; i++) {
            int L = tid + i * 256;
            int w_ = L >> 4, lc = L & 15;
            uint4 val = *(const uint4*)((const char*)sO + w_ * 256 + ((lc ^ (w_ & 7)) << 4));
            int hh = lc >> 2, sub = lc & 3;
            size_t off;
            if (m == 1) {
                int kv = h0 + hh;
                int q5 = kv & 31;
                int slot = (kv & ~31) | ((q5 & 4) << 2) | ((q5 & 24) >> 1) | (q5 & 3);
                off = (size_t)(b * 64 + w_) * 32768 + slot * 32 + (sub ^ ((slot >> 1) & 3)) * 8;
            } else {
                off = (size_t)(b * 64 + w_) * 32768 + (h0 + hh) * 32 + sub * 8;
            }
            *(uint4*)(gout + off) = val;
        }
    }
}

// ---------------------------------------------------------------------------
// Phase 2: attention — R13's VALIDATED kernel (48.6us) with two scheduling
// deltas only (no layout/liveness/math change):
//   1. pin 2->3 REMOVED: PV(nq) depends only on pf[nq], so the scheduler can
//      slide PV MFMAs under the remaining exps (R13 post-mortem: ~88% serial
//      pipe usage; this is the only register-neutral overlap left).
//   2. j-loop unroll 2: amortizes ~30 instr/j of loop/address overhead.
// Pin 1->2 and setprio kept (part of the R9->R10 +4.5us win).
// ---------------------------------------------------------------------------
__global__ __launch_bounds__(1024, 2) void attn(
    const u16* __restrict__ Qb, const u16* __restrict__ Kb,
    const u16* __restrict__ Vb, u16* __restrict__ Ow)
{
    __shared__ __align__(16) char sK[65536];
    __shared__ __align__(16) char sV[65536];
    const int tid = threadIdx.x;
    const int p = blockIdx.x;

    {
        const uint4* gK = (const uint4*)(Kb + (size_t)p * 32768);
        uint4* sK4 = (uint4*)sK;
        for (int m = tid; m < 4096; m += 1024)
            sK4[m] = gK[m];                 // linear: image prepared by qkv_proj
        const uint4* gV = (const uint4*)(Vb + (size_t)p * 32768);
        for (int m = tid; m < 4096; m += 1024) {
            uint4 val = gV[m];
            int kv = m >> 2, c0 = (m & 3) * 8;
            const u16* pv = (const u16*)&val;
#pragma unroll
            for (int k = 0; k < 8; k++) {
                int d = c0 + k;
                int chv = (kv >> 3) ^ (d & 7) ^ ((d >> 3) & 3);
                *(u16*)(sV + d * 2048 + (chv << 4) + (kv & 7) * 2) = pv[k];
            }
        }
    }
    __syncthreads();

    const int wid = tid >> 6, lane = tid & 63;
    const int g = lane >> 4, c = lane & 15;

    bf16x8 qf[4];
    {
        const u16* qbase = Qb + (size_t)p * 32768;
#pragma unroll
        for (int nq = 0; nq < 4; nq++) {
            int row = wid * 64 + nq * 16 + c;
            qf[nq] = __builtin_bit_cast(bf16x8, *(const uint4*)(qbase + row * 32 + g * 8));
        }
    }

    // ones A-fragment (bf16 1.0) for the row-sum MFMA
    bf16x8 ones;
    {
        uint4 u; u.x = u.y = u.z = u.w = 0x3F803F80u;
        ones = __builtin_bit_cast(bf16x8, u);
    }

    f32x4 o[4][2];
    f32x4 ls[4];
    const f32x4 zz = {0.f, 0.f, 0.f, 0.f};
#pragma unroll
    for (int nq = 0; nq < 4; nq++) { o[nq][0] = zz; o[nq][1] = zz; ls[nq] = zz; }

#pragma unroll 2
    for (int j = 0; j < 32; j++) {
        const int kv0 = j * 32;
        const int ra = kv0 + c;          // tile X slot row
        const int rb = ra + 16;          // tile Y slot row
        bf16x8 k0 = __builtin_bit_cast(bf16x8,
            *(const uint4*)(sK + ra * 64 + ((g ^ ((ra >> 1) & 3)) << 4)));
        bf16x8 k1 = __builtin_bit_cast(bf16x8,
            *(const uint4*)(sK + rb * 64 + ((g ^ ((rb >> 1) & 3)) << 4)));
        const int cb = (kv0 >> 3) + g;
        bf16x8 v0 = __builtin_bit_cast(bf16x8,
            *(const uint4*)(sV + c * 2048 + ((cb ^ (c & 7) ^ ((c >> 3) & 3)) << 4)));
        bf16x8 v1 = __builtin_bit_cast(bf16x8,
            *(const uint4*)(sV + (c + 16) * 2048 + ((cb ^ (c & 7) ^ (((c + 16) >> 3) & 3)) << 4)));

        // ---- phase 1: all QK^T MFMAs (8) ----
        f32x4 sA[4], sB_[4];
#pragma unroll
        for (int nq = 0; nq < 4; nq++) {
            sA[nq]  = __builtin_amdgcn_mfma_f32_16x16x32_bf16(k0, qf[nq], zz, 0, 0, 0);
            sB_[nq] = __builtin_amdgcn_mfma_f32_16x16x32_bf16(k1, qf[nq], zz, 0, 0, 0);
        }
        __builtin_amdgcn_sched_barrier(0);

        // ---- phase 2+3 fused region: exp/pack streams into PV/rowsum MFMAs.
        // No pin here: PV(nq) waits only on its own pf[nq], so MFMA issue
        // overlaps the remaining exps.
        __builtin_amdgcn_s_setprio(1);
#pragma unroll
        for (int nq = 0; nq < 4; nq++) {
            float p0[4], p1[4];
#pragma unroll
            for (int r = 0; r < 4; r++) {
                p0[r] = __builtin_amdgcn_exp2f(sA[nq][r]);   // scale folded into K
                p1[r] = __builtin_amdgcn_exp2f(sB_[nq][r]);
            }
            uint4 pw;
            pw.x = cvtpk(p0[0], p0[1]);   // kv 8g+0,1
            pw.y = cvtpk(p0[2], p0[3]);   // kv 8g+2,3
            pw.z = cvtpk(p1[0], p1[1]);   // kv 8g+4,5
            pw.w = cvtpk(p1[2], p1[3]);   // kv 8g+6,7
            bf16x8 pf = __builtin_bit_cast(bf16x8, pw);
            o[nq][0] = __builtin_amdgcn_mfma_f32_16x16x32_bf16(v0, pf, o[nq][0], 0, 0, 0);
            o[nq][1] = __builtin_amdgcn_mfma_f32_16x16x32_bf16(v1, pf, o[nq][1], 0, 0, 0);
            ls[nq]   = __builtin_amdgcn_mfma_f32_16x16x32_bf16(ones, pf, ls[nq], 0, 0, 0);
        }
        __builtin_amdgcn_s_setprio(0);
    }

#pragma unroll
    for (int nq = 0; nq < 4; nq++) {
        const float inv = 1.0f / ls[nq][0];   // every lane holds the full row-sum
        const int hq = wid * 64 + nq * 16 + c;
        u16* dst = Ow + (size_t)p * 32768 + hq;
#pragma unroll
        for (int t = 0; t < 2; t++)
#pragma unroll
            for (int r = 0; r < 4; r++) {
                int d = t * 16 + g * 4 + r;
                float v = o[nq][t][r] * inv;
                dst[(size_t)d * 1024] = (u16)cvtpk(v, v);   // lo16 = bf16(v)
            }
    }
}

// ---------------------------------------------------------------------------
// Phase 3: transpose Ow bf16 [pair][d][h] -> out f32 [b][d][h][w], fused
// *sum(w_lin)+b_lin. grid = 2048 blocks (b, d, h-tile of 64), 256 threads.
// (Validated R11-R13.)
// ---------------------------------------------------------------------------
__global__ __launch_bounds__(256) void finalize_tr(
    const u16* __restrict__ Ow, const float* __restrict__ w_lin,
    const float* __restrict__ b_lin, float* __restrict__ out)
{
    __shared__ float tile[64][65];
    const int tid = threadIdx.x;
    const int bi = blockIdx.x;
    const int b = bi >> 9, d = (bi >> 4) & 31, ht = bi & 15;
    const int h0 = ht * 64;

    float slin = 0.f;
#pragma unroll
    for (int i = 0; i < 8; i++) slin += w_lin[i];
    const float bl = b_lin[0];

    const int w = tid >> 2, part = tid & 3;
    const u16* src = Ow + (((size_t)b * 64 + w) * 32 + d) * 1024 + h0 + part * 16;
#pragma unroll
    for (int i = 0; i < 2; i++) {
        uint4 v = ((const uint4*)src)[i];            // 8 bf16
        int hh = part * 16 + i * 8;
        u32 a[4] = {v.x, v.y, v.z, v.w};
#pragma unroll
        for (int e = 0; e < 4; e++) {
            tile[w][hh + 2 * e]     = bf2f(a[e] & 0xFFFFu);
            tile[w][hh + 2 * e + 1] = bf2f(a[e] >> 16);
        }
    }
    __syncthreads();

    const int ww = tid & 63, hb = tid >> 6;
    const size_t obase = ((size_t)b * 32 + d) * 1024 + h0;
#pragma unroll
    for (int k = 0; k < 16; k++) {
        int hh = k * 4 + hb;
        out[(obase + hh) * 64 + ww] = tile[ww][hh] * slin + bl;
    }
}

// ---------------------------------------------------------------------------
extern "C" void kernel_launch(void* const* d_in, const int* in_sizes, int n_in,
                              void* d_out, int out_size, void* d_ws, size_t ws_size,
                              hipStream_t stream)
{
    const float* x  = (const float*)d_in[0];
    const float* wq = (const float*)d_in[1];
    const float* bq = (const float*)d_in[2];
    const float* wk = (const float*)d_in[3];
    const float* bk = (const float*)d_in[4];
    const float* wv = (const float*)d_in[5];
    const float* bv = (const float*)d_in[6];
    const float* wl = (const float*)d_in[7];
    const float* bl = (const float*)d_in[8];
    float* out = (float*)d_out;

    char* ws = (char*)d_ws;
    u16*   Qb = (u16*)(ws);                    // 16 MiB bf16 [256][1024][32]
    u16*   Kb = (u16*)(ws + (16u << 20));      // 16 MiB bf16, pre-scaled/permuted/swizzled
    u16*   Vb = (u16*)(ws + (32u << 20));      // 16 MiB bf16 [256][1024][32] pos-major
    u16*   Ow = (u16*)(ws + (48u << 20));      // 16 MiB bf16 [256][32][1024]

    qkv_proj<<<1024, 256, 0, stream>>>(x, wq, bq, wk, bk, wv, bv, Qb, Kb, Vb);
    attn<<<256, 1024, 0, stream>>>(Qb, Kb, Vb, Ow);
    finalize_tr<<<2048, 256, 0, stream>>>(Ow, wl, bl, out);
}